// Round 1
// baseline (3381.223 us; speedup 1.0000x reference)
//
#include <hip/hip_runtime.h>
#include <math.h>

// STGCN fused inference kernel.
// Every (b,n) pair is independent: temporal convs act on T only, ChebConv K=1
// is a per-node 32x32 linear, MLPs are per-node. One block = 32 pairs (same n,
// 32 consecutive b). All intermediates in LDS; per-stage weights staged into a
// reused LDS buffer. f32 throughout (no fp32 MFMA on CDNA4 -> vector ALU).

namespace {

constexpr int NT  = 512;              // 8 wave-groups of 64 lanes
constexpr int NP  = 32;               // (b,n) pairs per block
constexpr int NPG = NP / (NT / 64);   // pairs per group = 4
constexpr float INV_STD = 0.9999950000374997f; // 1/sqrt(1+1e-5)

struct Params {
  const float *x;
  const float *awp,*abp,*awq,*abq,*awr,*abr,*acw,*acb;
  const float *awp2,*abp2,*awq2,*abq2,*awr2,*abr2,*ag,*abeta;
  const float *bwp,*bbp,*bwq,*bbq,*bwr,*bbr,*bcw,*bcb;
  const float *bwp2,*bbp2,*bwq2,*bbq2,*bwr2,*bbr2,*bg,*bbeta;
  const float *w1,*b1,*w2,*b2;
  float *out;
};

__device__ __forceinline__ void cpyw(float* dst, const float* __restrict__ src, int nfloats){
  const int tid = threadIdx.x;
  const float4* s = (const float4*)src;
  float4* d = (float4*)dst;
  const int n4 = nfloats >> 2;
  for (int i = tid; i < n4; i += NT) d[i] = s[i];
}

// Global conv weights [3][CIN][COUT] -> LDS [3][CIN/4][COUT][4] so a lane's
// 4-ci weight chunk is one conflict-free ds_read_b128.
template<int CIN, int COUT>
__device__ __forceinline__ void cpyw_tcn(float* dst, const float* __restrict__ src){
  for (int i = threadIdx.x; i < 3*CIN*COUT; i += NT){
    const int co = i % COUT;
    const int r  = i / COUT;
    const int ci = r % CIN;
    const int kt = r / CIN;
    dst[((kt*(CIN/4) + (ci>>2))*COUT + co)*4 + (ci&3)] = src[i];
  }
}

// cw [32][32] -> [8][32][4]
__device__ __forceinline__ void cpyw_cheb(float* dst, const float* __restrict__ src){
  for (int i = threadIdx.x; i < 1024; i += NT){
    const int co = i & 31, ci = i >> 5;
    dst[((ci>>2)*32 + co)*4 + (ci&3)] = src[i];
  }
}

// Gated temporal conv: relu(P*sigmoid(Q)+R), optional eval-BN + outer relu.
// Lane mapping: co = lane % COUT, t-group = lane / COUT, TPT timesteps each.
template<int CIN, int TIN, int COUT, bool BN>
__device__ __forceinline__ void tcn_stage(const float* __restrict__ sW,
                                          const float* __restrict__ sIn,
                                          float* __restrict__ sOut,
                                          const int lane, const float bnsc, const float bnbt)
{
  constexpr int TOUTV  = TIN - 2;
  constexpr int GROUPS = 64 / COUT;
  constexpr int TPT    = (TOUTV + GROUPS - 1) / GROUPS;
  constexpr int S      = 3 * CIN * COUT;
  const int co = lane % COUT;
  const int tg = lane / COUT;

  float accP[TPT], accQ[TPT], accR[TPT];
  {
    const float bp = sW[3*S + co];
    const float bq = sW[3*S + COUT + co];
    const float br = sW[3*S + 2*COUT + co];
    #pragma unroll
    for (int j = 0; j < TPT; ++j){ accP[j]=bp; accQ[j]=bq; accR[j]=br; }
  }

  #pragma unroll
  for (int ci4 = 0; ci4 < CIN/4; ++ci4){
    float4 hv[TPT+2];
    #pragma unroll
    for (int j2 = 0; j2 < TPT+2; ++j2){
      const int tt = tg*TPT + j2;
      hv[j2] = (tt < TIN) ? *(const float4*)&sIn[tt*CIN + ci4*4]
                          : make_float4(0.f,0.f,0.f,0.f);
    }
    #pragma unroll
    for (int kt = 0; kt < 3; ++kt){
      const int wb = ((kt*(CIN/4) + ci4)*COUT + co)*4;
      const float4 wp = *(const float4*)&sW[wb];
      const float4 wq = *(const float4*)&sW[S + wb];
      const float4 wr = *(const float4*)&sW[2*S + wb];
      #pragma unroll
      for (int j = 0; j < TPT; ++j){
        const float4 h = hv[j+kt];
        accP[j] = fmaf(h.x, wp.x, accP[j]); accP[j] = fmaf(h.y, wp.y, accP[j]);
        accP[j] = fmaf(h.z, wp.z, accP[j]); accP[j] = fmaf(h.w, wp.w, accP[j]);
        accQ[j] = fmaf(h.x, wq.x, accQ[j]); accQ[j] = fmaf(h.y, wq.y, accQ[j]);
        accQ[j] = fmaf(h.z, wq.z, accQ[j]); accQ[j] = fmaf(h.w, wq.w, accQ[j]);
        accR[j] = fmaf(h.x, wr.x, accR[j]); accR[j] = fmaf(h.y, wr.y, accR[j]);
        accR[j] = fmaf(h.z, wr.z, accR[j]); accR[j] = fmaf(h.w, wr.w, accR[j]);
      }
    }
  }

  #pragma unroll
  for (int j = 0; j < TPT; ++j){
    const int t = tg*TPT + j;
    if (t < TOUTV){
      const float sig = 1.f / (1.f + expf(-accQ[j]));
      float v = fmaxf(fmaf(accP[j], sig, accR[j]), 0.f);
      if (BN) v = fmaxf(fmaf(v, bnsc, bnbt), 0.f);
      sOut[t*COUT + co] = v;
    }
  }
}

// Per-node 32x32 linear + relu (ChebConv K=1).
template<int TT>
__device__ __forceinline__ void cheb_stage(const float* __restrict__ sW,
                                           const float* __restrict__ sIn,
                                           float* __restrict__ sOut, const int lane)
{
  constexpr int TPT = TT/2;
  const int co = lane & 31;
  const int tg = lane >> 5;
  float acc[TPT];
  const float cb = sW[1024 + co];
  #pragma unroll
  for (int j=0;j<TPT;++j) acc[j] = cb;
  #pragma unroll
  for (int ci4 = 0; ci4 < 8; ++ci4){
    const float4 w = *(const float4*)&sW[(ci4*32 + co)*4];
    #pragma unroll
    for (int j=0;j<TPT;++j){
      const float4 h = *(const float4*)&sIn[(tg*TPT + j)*32 + ci4*4];
      acc[j] = fmaf(h.x, w.x, acc[j]); acc[j] = fmaf(h.y, w.y, acc[j]);
      acc[j] = fmaf(h.z, w.z, acc[j]); acc[j] = fmaf(h.w, w.w, acc[j]);
    }
  }
  #pragma unroll
  for (int j=0;j<TPT;++j) sOut[(tg*TPT+j)*32 + co] = fmaxf(acc[j], 0.f);
}

__global__ __launch_bounds__(NT, 2) void stgcn_fused(const Params p)
{
  __shared__ __align__(16) float sW[18624];      // stage weights (max: 3*3*32*64 + 192)
  __shared__ __align__(16) float big1[NP*384];   // ping
  __shared__ __align__(16) float big2[NP*256];   // pong
  __shared__ __align__(16) float sx[NP*40];      // input x tile

  const int tid  = threadIdx.x;
  const int lane = tid & 63;
  const int gid  = tid >> 6;
  const int tile = blockIdx.x;          // 113 * (1024/32) = 3616 tiles
  const int n    = tile >> 5;
  const int b0   = (tile & 31) * NP;

  // ---- S0: load x tile (32 pairs x 10 t x 4 ch, one float4 per (pair,t)) ----
  for (int i = tid; i < NP*10; i += NT){
    const int pr = i / 10;
    const int t  = i - pr*10;
    const int b  = b0 + pr;
    *(float4*)&sx[pr*40 + t*4] =
        *(const float4*)&p.x[(size_t)((b*10 + t)*113 + n)*4];
  }
  // S1 weights: TCN a1 (4->32)
  cpyw_tcn<4,32>(sW,      p.awp);
  cpyw_tcn<4,32>(sW+384,  p.awq);
  cpyw_tcn<4,32>(sW+768,  p.awr);
  cpyw(sW+1152, p.abp, 32); cpyw(sW+1184, p.abq, 32); cpyw(sW+1216, p.abr, 32);
  __syncthreads();

  #pragma unroll 1
  for (int k=0;k<NPG;++k){
    const int pr = gid*NPG + k;
    tcn_stage<4,10,32,false>(sW, sx + pr*40, big1 + pr*256, lane, 0.f, 0.f);
  }
  __syncthreads();

  // S2: Cheb a (32x32)
  cpyw_cheb(sW, p.acw); cpyw(sW+1024, p.acb, 32);
  __syncthreads();
  #pragma unroll 1
  for (int k=0;k<NPG;++k){
    const int pr = gid*NPG + k;
    cheb_stage<8>(sW, big1 + pr*256, big2 + pr*256, lane);
  }
  __syncthreads();

  // S3: TCN a2 (32->64) + BN + outer relu
  cpyw_tcn<32,64>(sW,       p.awp2);
  cpyw_tcn<32,64>(sW+6144,  p.awq2);
  cpyw_tcn<32,64>(sW+12288, p.awr2);
  cpyw(sW+18432, p.abp2, 64); cpyw(sW+18496, p.abq2, 64); cpyw(sW+18560, p.abr2, 64);
  __syncthreads();
  {
    const float bnsc = INV_STD * p.ag[n];
    const float bnbt = p.abeta[n];
    #pragma unroll 1
    for (int k=0;k<NPG;++k){
      const int pr = gid*NPG + k;
      tcn_stage<32,8,64,true>(sW, big2 + pr*256, big1 + pr*384, lane, bnsc, bnbt);
    }
  }
  __syncthreads();

  // S4: TCN b1 (64->32)
  cpyw_tcn<64,32>(sW,       p.bwp);
  cpyw_tcn<64,32>(sW+6144,  p.bwq);
  cpyw_tcn<64,32>(sW+12288, p.bwr);
  cpyw(sW+18432, p.bbp, 32); cpyw(sW+18464, p.bbq, 32); cpyw(sW+18496, p.bbr, 32);
  __syncthreads();
  #pragma unroll 1
  for (int k=0;k<NPG;++k){
    const int pr = gid*NPG + k;
    tcn_stage<64,6,32,false>(sW, big1 + pr*384, big2 + pr*128, lane, 0.f, 0.f);
  }
  __syncthreads();

  // S5: Cheb b (32x32)
  cpyw_cheb(sW, p.bcw); cpyw(sW+1024, p.bcb, 32);
  __syncthreads();
  #pragma unroll 1
  for (int k=0;k<NPG;++k){
    const int pr = gid*NPG + k;
    cheb_stage<4>(sW, big2 + pr*128, big1 + pr*128, lane);
  }
  __syncthreads();

  // S6: TCN b2 (32->16) + BN + outer relu
  cpyw_tcn<32,16>(sW,      p.bwp2);
  cpyw_tcn<32,16>(sW+1536, p.bwq2);
  cpyw_tcn<32,16>(sW+3072, p.bwr2);
  cpyw(sW+4608, p.bbp2, 16); cpyw(sW+4624, p.bbq2, 16); cpyw(sW+4640, p.bbr2, 16);
  __syncthreads();
  {
    const float bnsc = INV_STD * p.bg[n];
    const float bnbt = p.bbeta[n];
    #pragma unroll 1
    for (int k=0;k<NPG;++k){
      const int pr = gid*NPG + k;
      tcn_stage<32,4,16,true>(sW, big1 + pr*128, big2 + pr*32, lane, bnsc, bnbt);
    }
  }
  __syncthreads();

  // S7: per-node MLP layer 1 (32->64), weights from global (L1-resident, same n).
  // feat[f] = h4[t=f>>4][c=f&15] == big2[pr*32 + f] (layout already matches).
  {
    const float* w1n = p.w1 + (size_t)n*64*32;
    const float  b1v = p.b1[n*64 + lane];
    const float4* wrow = (const float4*)(w1n + lane*32);
    float4 wv[8];
    #pragma unroll
    for (int q=0;q<8;++q) wv[q] = wrow[q];
    #pragma unroll 1
    for (int k=0;k<NPG;++k){
      const int pr = gid*NPG + k;
      const float4* fv = (const float4*)&big2[pr*32];
      float acc = b1v;
      #pragma unroll
      for (int q=0;q<8;++q){
        const float4 f = fv[q];
        acc = fmaf(f.x, wv[q].x, acc); acc = fmaf(f.y, wv[q].y, acc);
        acc = fmaf(f.z, wv[q].z, acc); acc = fmaf(f.w, wv[q].w, acc);
      }
      big1[pr*64 + lane] = fmaxf(acc, 0.f);
    }
  }
  __syncthreads();

  // S8: per-node MLP layer 2 (64->3) + store
  if (lane < 3){
    const float* w2n = p.w2 + (size_t)n*3*64;
    const float4* wrow = (const float4*)(w2n + lane*64);
    float4 wv[16];
    #pragma unroll
    for (int q=0;q<16;++q) wv[q] = wrow[q];
    const float b2v = p.b2[n*3 + lane];
    #pragma unroll 1
    for (int k=0;k<NPG;++k){
      const int pr = gid*NPG + k;
      const float4* hv = (const float4*)&big1[pr*64];
      float acc = b2v;
      #pragma unroll
      for (int q=0;q<16;++q){
        const float4 h = hv[q];
        acc = fmaf(h.x, wv[q].x, acc); acc = fmaf(h.y, wv[q].y, acc);
        acc = fmaf(h.z, wv[q].z, acc); acc = fmaf(h.w, wv[q].w, acc);
      }
      const int b = b0 + pr;
      p.out[(size_t)(b*113 + n)*3 + lane] = acc;
    }
  }
}

} // namespace

extern "C" void kernel_launch(void* const* d_in, const int* in_sizes, int n_in,
                              void* d_out, int out_size, void* d_ws, size_t ws_size,
                              hipStream_t stream) {
  Params p;
  p.x     = (const float*)d_in[0];
  // d_in[1] = edge_index (unused: ChebConv K=1 keeps only the identity term)
  p.awp   = (const float*)d_in[2];  p.abp   = (const float*)d_in[3];
  p.awq   = (const float*)d_in[4];  p.abq   = (const float*)d_in[5];
  p.awr   = (const float*)d_in[6];  p.abr   = (const float*)d_in[7];
  p.acw   = (const float*)d_in[8];  p.acb   = (const float*)d_in[9];
  p.awp2  = (const float*)d_in[10]; p.abp2  = (const float*)d_in[11];
  p.awq2  = (const float*)d_in[12]; p.abq2  = (const float*)d_in[13];
  p.awr2  = (const float*)d_in[14]; p.abr2  = (const float*)d_in[15];
  p.ag    = (const float*)d_in[16]; p.abeta = (const float*)d_in[17];
  p.bwp   = (const float*)d_in[18]; p.bbp   = (const float*)d_in[19];
  p.bwq   = (const float*)d_in[20]; p.bbq   = (const float*)d_in[21];
  p.bwr   = (const float*)d_in[22]; p.bbr   = (const float*)d_in[23];
  p.bcw   = (const float*)d_in[24]; p.bcb   = (const float*)d_in[25];
  p.bwp2  = (const float*)d_in[26]; p.bbp2  = (const float*)d_in[27];
  p.bwq2  = (const float*)d_in[28]; p.bbq2  = (const float*)d_in[29];
  p.bwr2  = (const float*)d_in[30]; p.bbr2  = (const float*)d_in[31];
  p.bg    = (const float*)d_in[32]; p.bbeta = (const float*)d_in[33];
  p.w1    = (const float*)d_in[34]; p.b1    = (const float*)d_in[35];
  p.w2    = (const float*)d_in[36]; p.b2    = (const float*)d_in[37];
  p.out   = (float*)d_out;

  const int tiles = 113 * (1024 / NP);  // 3616
  stgcn_fused<<<tiles, NT, 0, stream>>>(p);
}

// Round 2
// 206.160 us; speedup vs baseline: 16.4010x; 16.4010x over previous
//
#include <hip/hip_runtime.h>
#include <math.h>

// STGCN fused, MFMA version.
// Key fact: temporal conv (1,3) over t with contiguous channels == GEMM whose
// im2col A-row is 3*CIN CONTIGUOUS elements in a [pr][t][ci] LDS buffer.
// All stages with K>=32 run as mfma_f32_16x16x32_bf16 (f32 accum, f32
// gating/BN epilogues); only the K=12 first conv stays f32 VALU.
// Strides chosen = 4 (mod 8) dwords: 16B-aligned b128 frags, ~2-way banks.

namespace {

constexpr int NT = 1024;              // 16 waves
constexpr int NP = 32;                // (b,n) pairs per block (same n)
constexpr float INV_STD = 0.9999950000374997f; // 1/sqrt(1+1e-5)

typedef __attribute__((ext_vector_type(8))) short  bf16x8;
typedef __attribute__((ext_vector_type(4))) short  s16x4;
typedef __attribute__((ext_vector_type(4))) float  f32x4;

__device__ __forceinline__ unsigned short f2bf(float f){   // RNE f32->bf16
  unsigned int u = __float_as_uint(f);
  u += 0x7fffu + ((u >> 16) & 1u);
  return (unsigned short)(u >> 16);
}
__device__ __forceinline__ f32x4 bcast(float v){ f32x4 r; r[0]=v; r[1]=v; r[2]=v; r[3]=v; return r; }

struct Params {
  const float *x;
  const float *awp,*abp,*awq,*abq,*awr,*abr,*acw,*acb;
  const float *awp2,*abp2,*awq2,*abq2,*awr2,*abr2,*ag,*abeta;
  const float *bwp,*bbp,*bwq,*bbq,*bwr,*bbr,*bcw,*bcb;
  const float *bwp2,*bbp2,*bwq2,*bbq2,*bwr2,*bbr2,*bg,*bbeta;
  const float *w1,*b1,*w2,*b2;
  float *out;
};

// ---- weight staging: global f32 [kt][ci][co] -> LDS bf16 W^T [co][k=kt*CIN+ci], row stride KP ----
template<int CIN, int COUT, int KP>
__device__ __forceinline__ void stage_conv_one(unsigned short* __restrict__ dst,
                                               const float* __restrict__ src){
  constexpr int ITEMS = 3*(CIN/4)*COUT;
  for (int i = threadIdx.x; i < ITEMS; i += NT){
    const int co  = i % COUT;
    const int r   = i / COUT;
    const int ci4 = r % (CIN/4);
    const int kt  = r / (CIN/4);
    const float* s = src + (kt*CIN + ci4*4)*COUT + co;
    s16x4 v; v[0]=(short)f2bf(s[0]); v[1]=(short)f2bf(s[COUT]);
    v[2]=(short)f2bf(s[2*COUT]); v[3]=(short)f2bf(s[3*COUT]);
    *reinterpret_cast<s16x4*>(dst + co*KP + kt*CIN + ci4*4) = v;
  }
}
template<int CIN, int COUT, int KP>
__device__ __forceinline__ void stage_conv_w(unsigned short* dst, const float* wp,
                                             const float* wq, const float* wr){
  stage_conv_one<CIN,COUT,KP>(dst,              wp);
  stage_conv_one<CIN,COUT,KP>(dst +   COUT*KP,  wq);
  stage_conv_one<CIN,COUT,KP>(dst + 2*COUT*KP,  wr);
}
// cheb cw[ci][co] -> dst[co*40 + ci]
__device__ __forceinline__ void stage_cheb(unsigned short* __restrict__ dst,
                                           const float* __restrict__ src){
  for (int i = threadIdx.x; i < 256; i += NT){
    const int co = i & 31, ci4 = i >> 5;
    const float* s = src + ci4*4*32 + co;
    s16x4 v; v[0]=(short)f2bf(s[0]); v[1]=(short)f2bf(s[32]);
    v[2]=(short)f2bf(s[64]); v[3]=(short)f2bf(s[96]);
    *reinterpret_cast<s16x4*>(dst + co*40 + ci4*4) = v;
  }
}
// mlp w1[h][f] (already K-contiguous) -> dst[h*40 + f]
__device__ __forceinline__ void stage_mlp1(unsigned short* __restrict__ dst,
                                           const float* __restrict__ src){
  for (int i = threadIdx.x; i < 512; i += NT){
    const int h = i >> 3, f4 = i & 7;
    const float4 w = *reinterpret_cast<const float4*>(src + h*32 + f4*4);
    s16x4 v; v[0]=(short)f2bf(w.x); v[1]=(short)f2bf(w.y);
    v[2]=(short)f2bf(w.z); v[3]=(short)f2bf(w.w);
    *reinterpret_cast<s16x4*>(dst + h*40 + f4*4) = v;
  }
}
// mlp w2[o][k] -> dst[o*72 + k], rows o=3..15 zero-filled
__device__ __forceinline__ void stage_mlp2(unsigned short* __restrict__ dst,
                                           const float* __restrict__ src){
  for (int i = threadIdx.x; i < 256; i += NT){
    const int o = i >> 4, k4 = i & 15;
    s16x4 v; v[0]=0; v[1]=0; v[2]=0; v[3]=0;
    if (o < 3){
      const float4 w = *reinterpret_cast<const float4*>(src + o*64 + k4*4);
      v[0]=(short)f2bf(w.x); v[1]=(short)f2bf(w.y);
      v[2]=(short)f2bf(w.z); v[3]=(short)f2bf(w.w);
    }
    *reinterpret_cast<s16x4*>(dst + o*72 + k4*4) = v;
  }
}

// ---- generic MFMA stage ----
// A row m=(pr,t): k-step ks reads 32 contiguous bf16 at [pr*PSTI + (t+kt)*RSTI + off].
// EPI: 0 = relu(acc+bias); 1 = relu(P*sig(Q)+R); 2 = EPI1 then relu(v*bnsc+bnbt).
template<int TOUT, int CIN, int COUT, int NK, int RSTI, int PSTI, int RSTO, int PSTO,
         int KP, int EPI, int MJOBS, int MSTEP>
__device__ __forceinline__ void mfma_stage(const unsigned short* __restrict__ aB,
    const unsigned short* __restrict__ wB, unsigned short* __restrict__ oB,
    const float* __restrict__ gb0, const float* __restrict__ gb1,
    const float* __restrict__ gb2,
    const int Mtile0, const int Ntile, const int lm, const int lk,
    const float bnsc, const float bnbt)
{
  const int col = Ntile*16 + lm;
  // preload B fragments (reused across MJOBS M-tiles)
  bf16x8 wp[NK], wq[NK], wr[NK];
  const unsigned short* wbase = wB + col*KP + lk*8;
  #pragma unroll
  for (int ks = 0; ks < NK; ++ks){
    wp[ks] = *reinterpret_cast<const bf16x8*>(wbase + ks*32);
    if constexpr (EPI >= 1){
      wq[ks] = *reinterpret_cast<const bf16x8*>(wbase +   COUT*KP + ks*32);
      wr[ks] = *reinterpret_cast<const bf16x8*>(wbase + 2*COUT*KP + ks*32);
    }
  }
  const float b0 = gb0[col];
  float b1v = 0.f, b2v = 0.f;
  if constexpr (EPI >= 1){ b1v = gb1[col]; b2v = gb2[col]; }

  #pragma unroll
  for (int j = 0; j < MJOBS; ++j){
    const int Mtile = Mtile0 + j*MSTEP;
    const int m  = Mtile*16 + lm;
    const int pr = m / TOUT;
    const int t  = m - pr*TOUT;
    f32x4 aP = bcast(b0), aQ, aR;
    if constexpr (EPI >= 1){ aQ = bcast(b1v); aR = bcast(b2v); }
    #pragma unroll
    for (int ks = 0; ks < NK; ++ks){
      int elem;
      if constexpr (CIN == 32) elem = pr*PSTI + (t + ks)*RSTI + lk*8;
      else                     elem = pr*PSTI + (t + (ks>>1))*RSTI + (ks&1)*32 + lk*8;
      const bf16x8 a = *reinterpret_cast<const bf16x8*>(aB + elem);
      aP = __builtin_amdgcn_mfma_f32_16x16x32_bf16(a, wp[ks], aP, 0, 0, 0);
      if constexpr (EPI >= 1){
        aQ = __builtin_amdgcn_mfma_f32_16x16x32_bf16(a, wq[ks], aQ, 0, 0, 0);
        aR = __builtin_amdgcn_mfma_f32_16x16x32_bf16(a, wr[ks], aR, 0, 0, 0);
      }
    }
    #pragma unroll
    for (int r = 0; r < 4; ++r){
      const int mo = Mtile*16 + lk*4 + r;
      const int po = mo / TOUT;
      const int to = mo - po*TOUT;
      float v;
      if constexpr (EPI == 0) v = fmaxf(aP[r], 0.f);
      else {
        const float sig = 1.f/(1.f + __expf(-aQ[r]));
        v = fmaxf(fmaf(aP[r], sig, aR[r]), 0.f);
        if constexpr (EPI == 2) v = fmaxf(fmaf(v, bnsc, bnbt), 0.f);
      }
      oB[po*PSTO + to*RSTO + col] = f2bf(v);
    }
  }
}

// ---- stage1: K=12 gated conv in f32 VALU, bf16 output ----
__device__ __forceinline__ void stage1_pair(const float* __restrict__ sWf,
    const float* __restrict__ sxp, unsigned short* __restrict__ outp, const int lane)
{
  const int co = lane & 31;
  const int tg = lane >> 5;     // 2 t-groups of 4
  float aP[4], aQ[4], aR[4];
  {
    const float bp = sWf[1152+co], bq = sWf[1184+co], br = sWf[1216+co];
    #pragma unroll
    for (int j=0;j<4;++j){ aP[j]=bp; aQ[j]=bq; aR[j]=br; }
  }
  float4 hv[6];
  #pragma unroll
  for (int j2=0;j2<6;++j2) hv[j2] = *reinterpret_cast<const float4*>(sxp + (tg*4+j2)*4);
  #pragma unroll
  for (int kt=0;kt<3;++kt){
    const int wb = (kt*32 + co)*4;
    const float4 wp = *reinterpret_cast<const float4*>(sWf + wb);
    const float4 wq = *reinterpret_cast<const float4*>(sWf + 384 + wb);
    const float4 wr = *reinterpret_cast<const float4*>(sWf + 768 + wb);
    #pragma unroll
    for (int j=0;j<4;++j){
      const float4 h = hv[j+kt];
      aP[j]=fmaf(h.x,wp.x,aP[j]); aP[j]=fmaf(h.y,wp.y,aP[j]); aP[j]=fmaf(h.z,wp.z,aP[j]); aP[j]=fmaf(h.w,wp.w,aP[j]);
      aQ[j]=fmaf(h.x,wq.x,aQ[j]); aQ[j]=fmaf(h.y,wq.y,aQ[j]); aQ[j]=fmaf(h.z,wq.z,aQ[j]); aQ[j]=fmaf(h.w,wq.w,aQ[j]);
      aR[j]=fmaf(h.x,wr.x,aR[j]); aR[j]=fmaf(h.y,wr.y,aR[j]); aR[j]=fmaf(h.z,wr.z,aR[j]); aR[j]=fmaf(h.w,wr.w,aR[j]);
    }
  }
  #pragma unroll
  for (int j=0;j<4;++j){
    const int t = tg*4 + j;
    const float sig = 1.f/(1.f + __expf(-aQ[j]));
    outp[t*40 + co] = f2bf(fmaxf(fmaf(aP[j], sig, aR[j]), 0.f));
  }
}

__global__ __launch_bounds__(NT, 4) void stgcn_fused(const Params p)
{
  // Layouts (elems, bf16): h1/h1c [pr:328][t:40][32]; h2 [pr:440][t:72][64];
  // h3/h3c [pr:168][t:40][32]; h4 [pr:40][t:16][16]; hid [pr:72][64].
  __shared__ float          sx[NP*40];          // f32 input tile
  __shared__ unsigned short bufA[14080];
  __shared__ unsigned short bufB[14080];
  __shared__ unsigned short sWs[19968];         // staged weights (max stage3: 3*64*104)
  float* sWf = reinterpret_cast<float*>(sWs);   // f32 view for stage1

  const int tid  = threadIdx.x;
  const int l    = tid & 63;
  const int wid  = tid >> 6;     // 0..15
  const int lm   = l & 15;
  const int lk   = l >> 4;
  const int tile = blockIdx.x;   // 113*32
  const int n    = tile >> 5;
  const int b0   = (tile & 31) * NP;

  // ---- phase 0: x tile + stage1 weights (f32) ----
  for (int i = tid; i < NP*10; i += NT){
    const int pr = i / 10, t = i - pr*10;
    *reinterpret_cast<float4*>(&sx[pr*40 + t*4]) =
      *reinterpret_cast<const float4*>(&p.x[(size_t)(((b0+pr)*10 + t)*113 + n)*4]);
  }
  for (int i = tid; i < 384; i += NT){           // [kt][ci][co] -> [(kt*1+ci4)*32+co]*4+(ci&3)
    const int co = i & 31, r = i >> 5, ci = r % 4, kt = r / 4;
    const float v = p.awp[i]; const float vq = p.awq[i]; const float vr = p.awr[i];
    const int d = (kt*32 + co)*4 + ci;
    sWf[d] = v; sWf[384 + d] = vq; sWf[768 + d] = vr;
  }
  if (tid < 32){ sWf[1152+tid]=p.abp[tid]; sWf[1184+tid]=p.abq[tid]; sWf[1216+tid]=p.abr[tid]; }
  __syncthreads();

  // ---- stage1: (10,4)->(8,32) f32 VALU -> bufA ----
  #pragma unroll
  for (int k=0;k<2;++k){
    const int pr = wid*2 + k;
    stage1_pair(sWf, sx + pr*40, bufA + pr*328, l);
  }
  __syncthreads();

  // ---- cheb1: (8,32)x(32,32) -> bufB.  M=256(16 tiles), N=32(2) ----
  stage_cheb(sWs, p.acw);
  __syncthreads();
  mfma_stage<8,32,32,1, 40,328, 40,328, 40, 0, 2,8>(
      bufA, sWs, bufB, p.acb, p.acb, p.acb, wid>>1, wid&1, lm, lk, 0.f, 0.f);
  __syncthreads();

  // ---- stage3: (8,32)->(6,64) gated conv + BN(a) -> bufA.  M=192(12), N=64(4) ----
  stage_conv_w<32,64,104>(sWs, p.awp2, p.awq2, p.awr2);
  __syncthreads();
  {
    const float bnsc = INV_STD * p.ag[n], bnbt = p.abeta[n];
    mfma_stage<6,32,64,3, 40,328, 72,440, 104, 2, 3,4>(
        bufB, sWs, bufA, p.abp2, p.abq2, p.abr2, wid>>2, wid&3, lm, lk, bnsc, bnbt);
  }
  __syncthreads();

  // ---- stage4: (6,64)->(4,32) gated conv -> bufB.  M=128(8), N=32(2) ----
  stage_conv_w<64,32,200>(sWs, p.bwp, p.bwq, p.bwr);
  __syncthreads();
  mfma_stage<4,64,32,6, 72,440, 40,168, 200, 1, 1,0>(
      bufA, sWs, bufB, p.bbp, p.bbq, p.bbr, wid>>1, wid&1, lm, lk, 0.f, 0.f);
  __syncthreads();

  // ---- cheb2: (4,32)x(32,32) -> bufA.  M=128(8), N=32(2) ----
  stage_cheb(sWs, p.bcw);
  __syncthreads();
  mfma_stage<4,32,32,1, 40,168, 40,168, 40, 0, 1,0>(
      bufB, sWs, bufA, p.bcb, p.bcb, p.bcb, wid>>1, wid&1, lm, lk, 0.f, 0.f);
  __syncthreads();

  // ---- stage6: (4,32)->(2,16) gated conv + BN(b) -> bufB (h4, flatten-ready). M=64(4), N=16(1) ----
  stage_conv_w<32,16,104>(sWs, p.bwp2, p.bwq2, p.bwr2);
  __syncthreads();
  if (wid < 4){
    const float bnsc = INV_STD * p.bg[n], bnbt = p.bbeta[n];
    mfma_stage<2,32,16,3, 40,168, 16,40, 104, 2, 1,0>(
        bufA, sWs, bufB, p.bbp2, p.bbq2, p.bbr2, wid, 0, lm, lk, bnsc, bnbt);
  }
  __syncthreads();

  // ---- mlp1: feat(32) x w1^T(32->64) -> bufA (hid).  M=32(2), N=64(4) ----
  stage_mlp1(sWs, p.w1 + (size_t)n*2048);
  __syncthreads();
  if (wid < 8){
    mfma_stage<1,32,64,1, 16,40, 32,72, 40, 0, 1,0>(
        bufB, sWs, bufA, p.b1 + n*64, p.b1, p.b1, wid&1, wid>>1, lm, lk, 0.f, 0.f);
  }
  __syncthreads();

  // ---- mlp2: hid(64) x w2^T(64->3) -> global.  M=32(2), N-tile 1 (3 valid cols) ----
  stage_mlp2(sWs, p.w2 + (size_t)n*192);
  __syncthreads();
  if (wid < 2){
    const int Mtile = wid;
    const float bias = (lm < 3) ? p.b2[n*3 + lm] : 0.f;
    f32x4 acc = bcast(bias);
    #pragma unroll
    for (int ks = 0; ks < 2; ++ks){
      const bf16x8 a = *reinterpret_cast<const bf16x8*>(bufA + (Mtile*16+lm)*72 + ks*32 + lk*8);
      const bf16x8 b = *reinterpret_cast<const bf16x8*>(sWs  + lm*72 + ks*32 + lk*8);
      acc = __builtin_amdgcn_mfma_f32_16x16x32_bf16(a, b, acc, 0, 0, 0);
    }
    if (lm < 3){
      #pragma unroll
      for (int r = 0; r < 4; ++r){
        const int pr = Mtile*16 + lk*4 + r;
        p.out[(size_t)((b0+pr)*113 + n)*3 + lm] = acc[r];
      }
    }
  }
}

} // namespace

extern "C" void kernel_launch(void* const* d_in, const int* in_sizes, int n_in,
                              void* d_out, int out_size, void* d_ws, size_t ws_size,
                              hipStream_t stream) {
  (void)in_sizes; (void)n_in; (void)d_ws; (void)ws_size; (void)out_size;
  Params p;
  p.x     = (const float*)d_in[0];
  // d_in[1] = edge_index (unused: ChebConv K=1 keeps only the identity term)
  p.awp   = (const float*)d_in[2];  p.abp   = (const float*)d_in[3];
  p.awq   = (const float*)d_in[4];  p.abq   = (const float*)d_in[5];
  p.awr   = (const float*)d_in[6];  p.abr   = (const float*)d_in[7];
  p.acw   = (const float*)d_in[8];  p.acb   = (const float*)d_in[9];
  p.awp2  = (const float*)d_in[10]; p.abp2  = (const float*)d_in[11];
  p.awq2  = (const float*)d_in[12]; p.abq2  = (const float*)d_in[13];
  p.awr2  = (const float*)d_in[14]; p.abr2  = (const float*)d_in[15];
  p.ag    = (const float*)d_in[16]; p.abeta = (const float*)d_in[17];
  p.bwp   = (const float*)d_in[18]; p.bbp   = (const float*)d_in[19];
  p.bwq   = (const float*)d_in[20]; p.bbq   = (const float*)d_in[21];
  p.bwr   = (const float*)d_in[22]; p.bbr   = (const float*)d_in[23];
  p.bcw   = (const float*)d_in[24]; p.bcb   = (const float*)d_in[25];
  p.bwp2  = (const float*)d_in[26]; p.bbp2  = (const float*)d_in[27];
  p.bwq2  = (const float*)d_in[28]; p.bbq2  = (const float*)d_in[29];
  p.bwr2  = (const float*)d_in[30]; p.bbr2  = (const float*)d_in[31];
  p.bg    = (const float*)d_in[32]; p.bbeta = (const float*)d_in[33];
  p.w1    = (const float*)d_in[34]; p.b1    = (const float*)d_in[35];
  p.w2    = (const float*)d_in[36]; p.b2    = (const float*)d_in[37];
  p.out   = (float*)d_out;

  const int tiles = 113 * (1024 / NP);  // 3616 blocks, 1 per CU-slot wavefrontwise
  stgcn_fused<<<tiles, NT, 0, stream>>>(p);
}